// Round 2
// baseline (127.297 us; speedup 1.0000x reference)
//
#include <hip/hip_runtime.h>

// Problem constants (match reference setup_inputs)
#define BATCH 2048
#define NPTS  8192

// convert_to_radar_frame constants
// cart_min_range = (640/2 - 0.5) * 0.2592
#define RES 0.2592f
#define CMR 82.8144f

__device__ __forceinline__ float wave_reduce_add(float v) {
    #pragma unroll
    for (int off = 32; off > 0; off >>= 1) v += __shfl_down(v, off, 64);
    return v;
}

struct Acc {
    float W, Sx, Sy, Tx, Ty, XX, XY, YX, YY;
    __device__ __forceinline__ void init() {
        W = Sx = Sy = Tx = Ty = XX = XY = YX = YY = 0.f;
    }
    // accumulate one point (already-converted coords)
    __device__ __forceinline__ void add(float wv, float sx, float sy, float tx, float ty) {
        float wtx = wv * tx, wty = wv * ty;
        W  += wv;
        Sx = fmaf(wv, sx, Sx);   Sy = fmaf(wv, sy, Sy);
        Tx += wtx;               Ty += wty;
        XX = fmaf(wtx, sx, XX);  XY = fmaf(wtx, sy, XY);
        YX = fmaf(wty, sx, YX);  YY = fmaf(wty, sy, YY);
    }
};

__global__ __launch_bounds__(256, 8) void svd_align_kernel(
    const float* __restrict__ src, const float* __restrict__ tgt,
    const float* __restrict__ wts, const int* __restrict__ cvt_flag,
    float* __restrict__ out)
{
    const int b   = blockIdx.x;
    const int tid = threadIdx.x;
    const int convert = *cvt_flag;  // wave-uniform branch

    const float4* s4  = (const float4*)(src + (size_t)b * NPTS * 2);
    const float4* t4  = (const float4*)(tgt + (size_t)b * NPTS * 2);
    const float2* w2p = (const float2*)(wts + (size_t)b * NPTS);

    // Two independent accumulator sets: halves the dependent-FMA chain and
    // lets the compiler overlap two point-streams.
    Acc a0, a1;
    a0.init(); a1.init();

    // 16 iterations x (2 points/thread), coalesced float4/float2 streams.
    // unroll 8 => 24 loads batched per chunk for deep MLP (VGPR budget 64).
    #pragma unroll 8
    for (int i = 0; i < 16; ++i) {
        const int k = i * 256 + tid;          // float4 index into [N*2] floats
        float4 s = s4[k];
        float4 t = t4[k];
        float2 w = w2p[k];

        float sx0, sy0, sx1, sy1, tx0, ty0, tx1, ty1;
        if (convert) {
            sx0 = fmaf(-RES, s.y, CMR);  sy0 = fmaf(RES, s.x, -CMR);
            sx1 = fmaf(-RES, s.w, CMR);  sy1 = fmaf(RES, s.z, -CMR);
            tx0 = fmaf(-RES, t.y, CMR);  ty0 = fmaf(RES, t.x, -CMR);
            tx1 = fmaf(-RES, t.w, CMR);  ty1 = fmaf(RES, t.z, -CMR);
        } else {
            sx0 = s.x; sy0 = s.y; sx1 = s.z; sy1 = s.w;
            tx0 = t.x; ty0 = t.y; tx1 = t.z; ty1 = t.w;
        }

        a0.add(w.x, sx0, sy0, tx0, ty0);   // even point -> set 0
        a1.add(w.y, sx1, sy1, tx1, ty1);   // odd point  -> set 1
    }

    // merge the two sets
    a0.W  += a1.W;
    a0.Sx += a1.Sx;  a0.Sy += a1.Sy;
    a0.Tx += a1.Tx;  a0.Ty += a1.Ty;
    a0.XX += a1.XX;  a0.XY += a1.XY;
    a0.YX += a1.YX;  a0.YY += a1.YY;

    // wave64 reduce each accumulator
    a0.W  = wave_reduce_add(a0.W);
    a0.Sx = wave_reduce_add(a0.Sx);  a0.Sy = wave_reduce_add(a0.Sy);
    a0.Tx = wave_reduce_add(a0.Tx);  a0.Ty = wave_reduce_add(a0.Ty);
    a0.XX = wave_reduce_add(a0.XX);  a0.XY = wave_reduce_add(a0.XY);
    a0.YX = wave_reduce_add(a0.YX);  a0.YY = wave_reduce_add(a0.YY);

    __shared__ float red[4][9];
    const int wave = tid >> 6;
    if ((tid & 63) == 0) {
        red[wave][0] = a0.W;
        red[wave][1] = a0.Sx; red[wave][2] = a0.Sy;
        red[wave][3] = a0.Tx; red[wave][4] = a0.Ty;
        red[wave][5] = a0.XX; red[wave][6] = a0.XY;
        red[wave][7] = a0.YX; red[wave][8] = a0.YY;
    }
    __syncthreads();

    if (tid == 0) {
        double Sw = 0, Ssx = 0, Ssy = 0, Stx = 0, Sty = 0;
        double Sxx = 0, Sxy = 0, Syx = 0, Syy = 0;
        #pragma unroll
        for (int i = 0; i < 4; ++i) {
            Sw  += red[i][0];
            Ssx += red[i][1]; Ssy += red[i][2];
            Stx += red[i][3]; Sty += red[i][4];
            Sxx += red[i][5]; Sxy += red[i][6];
            Syx += red[i][7]; Syy += red[i][8];
        }

        const double wd  = Sw + 1e-4;
        const double scx = Ssx / wd, scy = Ssy / wd;
        const double tcx = Stx / wd, tcy = Sty / wd;

        // W[d][e] = (sum w*t_d*s_e - tc_d*sum(w s_e) - sc_e*sum(w t_d) + tc_d*sc_e*Sw)/wd
        const double W00 = (Sxx - tcx * Ssx - scx * Stx + tcx * scx * Sw) / wd;
        const double W01 = (Sxy - tcx * Ssy - scy * Stx + tcx * scy * Sw) / wd;
        const double W10 = (Syx - tcy * Ssx - scx * Sty + tcy * scx * Sw) / wd;
        const double W11 = (Syy - tcy * Ssy - scy * Sty + tcy * scy * Sw) / wd;

        const double det = W00 * W11 - W01 * W10;

        // 2x2 orthogonal polar factor of W (== U2 @ V2^T from SVD), plus
        // R[2][2] = sign(det) from the Kabsch diag(1,1,detU*detV) correction.
        double R00, R01, R10, R11, dsign;
        if (det >= 0.0) {
            const double p = W00 + W11;
            const double q = W10 - W01;
            double r = sqrt(p * p + q * q);
            if (r > 0.0) {
                R00 = p / r;  R01 = -q / r;
                R10 = q / r;  R11 = p / r;
            } else {
                R00 = 1.0; R01 = 0.0; R10 = 0.0; R11 = 1.0;
            }
            dsign = 1.0;
        } else {
            const double p = W00 - W11;
            const double q = W01 + W10;
            const double r = sqrt(p * p + q * q);  // > 0 when det < 0
            R00 = p / r;   R01 = q / r;
            R10 = q / r;   R11 = -p / r;
            dsign = -1.0;
        }

        // t_tgt_src_insrc = src_centroid - R^T @ tgt_centroid (z == 0)
        const double tt0 = scx - (R00 * tcx + R10 * tcy);
        const double tt1 = scy - (R01 * tcx + R11 * tcy);
        // t_src_tgt_intgt = -R @ t_tgt_src_insrc
        const double o0 = -(R00 * tt0 + R01 * tt1);
        const double o1 = -(R10 * tt0 + R11 * tt1);

        // Output 0: R^T, row-major [3][3]
        float* oR = out + (size_t)b * 9;
        oR[0] = (float)R00; oR[1] = (float)R10; oR[2] = 0.f;
        oR[3] = (float)R01; oR[4] = (float)R11; oR[5] = 0.f;
        oR[6] = 0.f;        oR[7] = 0.f;        oR[8] = (float)dsign;

        // Output 1: translation [3][1]
        float* oT = out + (size_t)BATCH * 9 + (size_t)b * 3;
        oT[0] = (float)o0; oT[1] = (float)o1; oT[2] = 0.f;
    }
}

extern "C" void kernel_launch(void* const* d_in, const int* in_sizes, int n_in,
                              void* d_out, int out_size, void* d_ws, size_t ws_size,
                              hipStream_t stream) {
    const float* src = (const float*)d_in[0];
    const float* tgt = (const float*)d_in[1];
    const float* wts = (const float*)d_in[2];
    const int*   cvt = (const int*)d_in[3];
    float* out = (float*)d_out;

    svd_align_kernel<<<BATCH, 256, 0, stream>>>(src, tgt, wts, cvt, out);
}

// Round 3
// 92.102 us; speedup vs baseline: 1.3821x; 1.3821x over previous
//
#include <hip/hip_runtime.h>

// Problem constants (match reference setup_inputs)
#define BATCH 2048
#define NPTS  8192

// convert_to_radar_frame constants
// cart_min_range = (640/2 - 0.5) * 0.2592
#define RES 0.2592f
#define CMR 82.8144f

__device__ __forceinline__ float wave_reduce_add(float v) {
    #pragma unroll
    for (int off = 32; off > 0; off >>= 1) v += __shfl_down(v, off, 64);
    return v;
}

__global__ __launch_bounds__(256, 4) void svd_align_kernel(
    const float* __restrict__ src, const float* __restrict__ tgt,
    const float* __restrict__ wts, const int* __restrict__ cvt_flag,
    float* __restrict__ out)
{
    const int b   = blockIdx.x;
    const int tid = threadIdx.x;
    const int convert = *cvt_flag;  // uniform

    // Branch-free conversion: out_x = fmaf(Ax, (convert? in_y : in_x), Bx)
    //                         out_y = fmaf(Ay, (convert? in_x : in_y), By)
    // convert=1: mx = -RES*y + CMR ; my = RES*x - CMR.  convert=0: identity.
    const float Ax = convert ? -RES : 1.0f;
    const float Bx = convert ?  CMR : 0.0f;
    const float Ay = convert ?  RES : 1.0f;
    const float By = convert ? -CMR : 0.0f;

    const float4* s4  = (const float4*)(src + (size_t)b * NPTS * 2);
    const float4* t4  = (const float4*)(tgt + (size_t)b * NPTS * 2);
    const float2* w2p = (const float2*)(wts + (size_t)b * NPTS);

    // 9 accumulators
    float aW = 0.f, aSx = 0.f, aSy = 0.f, aTx = 0.f, aTy = 0.f;
    float aXX = 0.f, aXY = 0.f, aYX = 0.f, aYY = 0.f;

    // distance-2 software prefetch: 3 buffers rotating, fully unrolled so
    // rotation is pure register renaming. Straight-line body (no branches)
    // so the scheduler can hoist loads freely.
    float4 sA = s4[tid],        tA = t4[tid];        float2 wA = w2p[tid];
    float4 sB = s4[tid + 256],  tB = t4[tid + 256];  float2 wB = w2p[tid + 256];

    #pragma unroll
    for (int i = 0; i < 16; ++i) {
        float4 sN, tN; float2 wN;
        if (i + 2 < 16) {               // compile-time predicate (full unroll)
            const int k = (i + 2) * 256 + tid;
            sN = s4[k]; tN = t4[k]; wN = w2p[k];
        }

        // ---- process buffer A (2 points) ----
        {
            float sx0 = fmaf(Ax, convert ? sA.y : sA.x, Bx);
            float sy0 = fmaf(Ay, convert ? sA.x : sA.y, By);
            float sx1 = fmaf(Ax, convert ? sA.w : sA.z, Bx);
            float sy1 = fmaf(Ay, convert ? sA.z : sA.w, By);
            float tx0 = fmaf(Ax, convert ? tA.y : tA.x, Bx);
            float ty0 = fmaf(Ay, convert ? tA.x : tA.y, By);
            float tx1 = fmaf(Ax, convert ? tA.w : tA.z, Bx);
            float ty1 = fmaf(Ay, convert ? tA.z : tA.w, By);

            float wv = wA.x;
            float wtx = wv * tx0, wty = wv * ty0;
            aW  += wv;
            aSx = fmaf(wv, sx0, aSx);  aSy = fmaf(wv, sy0, aSy);
            aTx += wtx;                aTy += wty;
            aXX = fmaf(wtx, sx0, aXX); aXY = fmaf(wtx, sy0, aXY);
            aYX = fmaf(wty, sx0, aYX); aYY = fmaf(wty, sy0, aYY);

            wv = wA.y;
            wtx = wv * tx1; wty = wv * ty1;
            aW  += wv;
            aSx = fmaf(wv, sx1, aSx);  aSy = fmaf(wv, sy1, aSy);
            aTx += wtx;                aTy += wty;
            aXX = fmaf(wtx, sx1, aXX); aXY = fmaf(wtx, sy1, aXY);
            aYX = fmaf(wty, sx1, aYX); aYY = fmaf(wty, sy1, aYY);
        }

        // rotate buffers (register renaming after unroll)
        sA = sB; tA = tB; wA = wB;
        sB = sN; tB = tN; wB = wN;
    }

    // wave64 reduce each accumulator
    aW  = wave_reduce_add(aW);
    aSx = wave_reduce_add(aSx);  aSy = wave_reduce_add(aSy);
    aTx = wave_reduce_add(aTx);  aTy = wave_reduce_add(aTy);
    aXX = wave_reduce_add(aXX);  aXY = wave_reduce_add(aXY);
    aYX = wave_reduce_add(aYX);  aYY = wave_reduce_add(aYY);

    __shared__ float red[4][9];
    const int wave = tid >> 6;
    if ((tid & 63) == 0) {
        red[wave][0] = aW;
        red[wave][1] = aSx; red[wave][2] = aSy;
        red[wave][3] = aTx; red[wave][4] = aTy;
        red[wave][5] = aXX; red[wave][6] = aXY;
        red[wave][7] = aYX; red[wave][8] = aYY;
    }
    __syncthreads();

    if (tid == 0) {
        double Sw = 0, Ssx = 0, Ssy = 0, Stx = 0, Sty = 0;
        double Sxx = 0, Sxy = 0, Syx = 0, Syy = 0;
        #pragma unroll
        for (int i = 0; i < 4; ++i) {
            Sw  += red[i][0];
            Ssx += red[i][1]; Ssy += red[i][2];
            Stx += red[i][3]; Sty += red[i][4];
            Sxx += red[i][5]; Sxy += red[i][6];
            Syx += red[i][7]; Syy += red[i][8];
        }

        const double wd  = Sw + 1e-4;
        const double scx = Ssx / wd, scy = Ssy / wd;
        const double tcx = Stx / wd, tcy = Sty / wd;

        // W[d][e] = (sum w*t_d*s_e - tc_d*sum(w s_e) - sc_e*sum(w t_d) + tc_d*sc_e*Sw)/wd
        const double W00 = (Sxx - tcx * Ssx - scx * Stx + tcx * scx * Sw) / wd;
        const double W01 = (Sxy - tcx * Ssy - scy * Stx + tcx * scy * Sw) / wd;
        const double W10 = (Syx - tcy * Ssx - scx * Sty + tcy * scx * Sw) / wd;
        const double W11 = (Syy - tcy * Ssy - scy * Sty + tcy * scy * Sw) / wd;

        const double det = W00 * W11 - W01 * W10;

        // 2x2 orthogonal polar factor of W (== U2 @ V2^T from SVD), plus
        // R[2][2] = sign(det) from the Kabsch diag(1,1,detU*detV) correction.
        double R00, R01, R10, R11, dsign;
        if (det >= 0.0) {
            const double p = W00 + W11;
            const double q = W10 - W01;
            double r = sqrt(p * p + q * q);
            if (r > 0.0) {
                R00 = p / r;  R01 = -q / r;
                R10 = q / r;  R11 = p / r;
            } else {
                R00 = 1.0; R01 = 0.0; R10 = 0.0; R11 = 1.0;
            }
            dsign = 1.0;
        } else {
            const double p = W00 - W11;
            const double q = W01 + W10;
            const double r = sqrt(p * p + q * q);  // > 0 when det < 0
            R00 = p / r;   R01 = q / r;
            R10 = q / r;   R11 = -p / r;
            dsign = -1.0;
        }

        // t_tgt_src_insrc = src_centroid - R^T @ tgt_centroid (z == 0)
        const double tt0 = scx - (R00 * tcx + R10 * tcy);
        const double tt1 = scy - (R01 * tcx + R11 * tcy);
        // t_src_tgt_intgt = -R @ t_tgt_src_insrc
        const double o0 = -(R00 * tt0 + R01 * tt1);
        const double o1 = -(R10 * tt0 + R11 * tt1);

        // Output 0: R^T, row-major [3][3]
        float* oR = out + (size_t)b * 9;
        oR[0] = (float)R00; oR[1] = (float)R10; oR[2] = 0.f;
        oR[3] = (float)R01; oR[4] = (float)R11; oR[5] = 0.f;
        oR[6] = 0.f;        oR[7] = 0.f;        oR[8] = (float)dsign;

        // Output 1: translation [3][1]
        float* oT = out + (size_t)BATCH * 9 + (size_t)b * 3;
        oT[0] = (float)o0; oT[1] = (float)o1; oT[2] = 0.f;
    }
}

extern "C" void kernel_launch(void* const* d_in, const int* in_sizes, int n_in,
                              void* d_out, int out_size, void* d_ws, size_t ws_size,
                              hipStream_t stream) {
    const float* src = (const float*)d_in[0];
    const float* tgt = (const float*)d_in[1];
    const float* wts = (const float*)d_in[2];
    const int*   cvt = (const int*)d_in[3];
    float* out = (float*)d_out;

    svd_align_kernel<<<BATCH, 256, 0, stream>>>(src, tgt, wts, cvt, out);
}